// Round 9
// baseline (89.738 us; speedup 1.0000x reference)
//
#include <hip/hip_runtime.h>
#include <hip/hip_fp16.h>

#define VOL    256
#define NPROJ  256
#define NDET   384
#define NS     256
#define PROW   129                 // texture row stride in DWORDS (258 halves)
#define PHR    132                 // rows staged per half (incl. margin)
#define PHD    (PHR * PROW)        // 17028 dwords = 68,112 B per half
#define PH4    (PHD / 4)           // 4257 uint4
#define ROWB   126                 // global row base of half h=1
#define NBATCH 2
#define TPB    768                 // 12 waves; 512 blocks -> 2 blocks/CU

typedef _Float16 hvec2 __attribute__((ext_vector_type(2)));

#if defined(__has_builtin)
#if __has_builtin(__builtin_amdgcn_fdot2)
#define HAS_FDOT2 1
#endif
#endif

// Half-texture builder: dst[((b*2)+h)*PHD + rowl*PROW + q] =
//   half2{ P(uy,2q), P(uy,2q+1) },  uy = rowl + h*ROWB,
//   P(uy,ux) = img[uy-1][ux-1], zero outside.
__global__ void pad_build_kernel(const float* __restrict__ src, uint* __restrict__ dst) {
    int idx = blockIdx.x * blockDim.x + threadIdx.x;   // over NBATCH*2*PHD
    if (idx >= NBATCH * 2 * PHD) return;
    int bh   = idx / PHD;                              // b*2+h
    int dd   = idx - bh * PHD;
    int rowl = dd / PROW;
    int q    = dd - rowl * PROW;
    int uy   = rowl + (bh & 1) * ROWB;
    int r    = uy - 1;
    int c0   = 2 * q - 1;
    const float* im = src + ((bh >> 1) << 16);
    float v0 = 0.0f, v1 = 0.0f;
    if ((unsigned)r < 256u) {
        const float* rp = im + (r << 8);
        if ((unsigned)c0 < 256u)       v0 = rp[c0];
        if ((unsigned)(c0 + 1) < 256u) v1 = rp[c0 + 1];
    }
    __half2 h2 = __floats2half2_rn(v0, v1);
    dst[idx] = *reinterpret_cast<uint*>(&h2);
}

// Two blocks per 768-ray group: h=0 handles samples with Y<129 (rows 0..131
// staged), h=1 handles Y>=129 (rows 126..257). Partials atomicAdd'ed to out.
__global__ __launch_bounds__(TPB) void fanproj_kernel(const uint4* __restrict__ G,
                                                      float* __restrict__ out) {
    __shared__ uint4 s4[PH4];                          // 68,112 B -> 2 blocks/CU
    const uint* sImg = reinterpret_cast<const uint*>(s4);

    int tid = threadIdx.x;
    int h   = blockIdx.x & 1;
    int grp = blockIdx.x >> 1;
    int ray = grp * TPB + tid;                         // b*P*D + p*D + d
    int b   = grp >> 7;                                // 128 groups per batch

    // contiguous uint4 stage of this (batch, half) texture
    {
        const uint4* gb = G + (size_t)((b << 1) + h) * PH4;
        for (int i = tid; i < PH4; i += TPB) s4[i] = gb[i];
    }

    int d  = ray % NDET;
    int pb = ray / NDET;
    int p  = pb & (NPROJ - 1);

    const float dt = 1.4142135623730951f;              // diag / NS = sqrt(2)
    const float t0 = 219.68777079743137f;              // SID - diag/2 + 0.5*dt

    float theta = (float)p * (6.283185307179586f / (float)NPROJ);
    float st, ct;
    __sincosf(theta, &st, &ct);

    float srcx = -400.0f * ct;
    float srcy = -400.0f * st;
    float off  = ((float)d - 191.5f) * 1.2f;
    float rx   = fmaf(800.0f, ct, -off * st);
    float ry   = fmaf(800.0f, st,  off * ct);
    float n2   = rx * rx + ry * ry;
    float rn   = rsqrtf(n2);
    rn = rn * (1.5f - 0.5f * n2 * rn * rn);            // one Newton step
    rx *= rn;
    ry *= rn;

    // padded-texture coords: X(s) = bxu + s*sx, valid when X,Y in [0,257)
    float bxu = fmaf(t0, rx, srcx) + 128.5f;
    float byu = fmaf(t0, ry, srcy) + 128.5f;
    float sx  = dt * rx;
    float sy  = dt * ry;

    // global guard-free interval (EPS-shrunk; border samples ~zero weight)
    const float EPS = 2e-3f;
    float sxs = (fabsf(sx) < 1e-9f) ? copysignf(1e-9f, sx) : sx;
    float sys = (fabsf(sy) < 1e-9f) ? copysignf(1e-9f, sy) : sy;
    float isx = 1.0f / sxs;
    float isy = 1.0f / sys;
    float ax0 = (0.0f - bxu) * isx, ax1 = (257.0f - bxu) * isx;
    float ay0 = (0.0f - byu) * isy, ay1 = (257.0f - byu) * isy;
    float lo  = fmaxf(fminf(ax0, ax1), fminf(ay0, ay1)) + EPS;
    float hi  = fminf(fmaxf(ax0, ax1), fmaxf(ay0, ay1)) - EPS;
    lo = fminf(fmaxf(lo, -1.0f), 300.0f);
    hi = fminf(fmaxf(hi, -1.0f), 300.0f);
    int slo = max(0,      (int)ceilf(lo));
    int shi = min(NS - 1, (int)floorf(hi));

    // exact complementary split at Y = 129 (identical float ops in both blocks)
    float tS = (129.0f - byu) * isy;
    tS = fminf(fmaxf(tS, -2.0f), 300.0f);
    int  kUp = (int)ceilf(tS);                         // split when sy > 0
    int  kDn = (int)floorf(tS) + 1;                    // split when sy < 0
    bool pos = (sys > 0.0f);
    int myLo, myHi;
    if (h == 0) {                                      // low-Y half
        myLo = pos ? slo : max(slo, kDn);
        myHi = pos ? min(shi, kUp - 1) : shi;
    } else {                                           // high-Y half
        myLo = pos ? max(slo, kUp) : slo;
        myHi = pos ? shi : min(shi, kDn - 1);
    }
    if (h) byu -= (float)ROWB;                         // local-row coordinates

    __syncthreads();                                   // LDS half-image ready

    float acc = 0.0f;
    float sf  = (float)myLo;
    for (int s = myLo; s <= myHi; ++s) {
        float X = fmaf(sf, sx, bxu);
        float Y = fmaf(sf, sy, byu);
        sf += 1.0f;
        float Xf = floorf(X);
        float Yf = floorf(Y);
        float wx = X - Xf;
        float wy = Y - Yf;
        int ux = (int)Xf;                              // in [0,256]
        int uy = (int)Yf;                              // local row in [0,130]
        int base = uy * PROW + (ux >> 1);
        uint d0 = sImg[base];                          // merge -> ds_read2_b32
        uint d1 = sImg[base + 1];
        uint d2 = sImg[base + PROW];                   // merge -> ds_read2_b32
        uint d3 = sImg[base + PROW + 1];
        unsigned sh = (unsigned)(ux & 1) << 4;
        uint tw = __builtin_amdgcn_alignbit(d1, d0, sh);
        uint bw = __builtin_amdgcn_alignbit(d3, d2, sh);
#ifdef HAS_FDOT2
        hvec2 hx = __builtin_bit_cast(hvec2, __builtin_amdgcn_cvt_pkrtz(1.0f - wx, wx));
        hvec2 tv = __builtin_bit_cast(hvec2, tw);
        hvec2 bv = __builtin_bit_cast(hvec2, bw);
        float top = __builtin_amdgcn_fdot2(tv, hx, 0.0f, false);
        float bot = __builtin_amdgcn_fdot2(bv, hx, 0.0f, false);
        acc = fmaf(wy, bot - top, acc + top);
#else
        __half2 ht = *reinterpret_cast<__half2*>(&tw);
        __half2 hb = *reinterpret_cast<__half2*>(&bw);
        float2 rt = __half22float2(ht);
        float2 rb = __half22float2(hb);
        float top = fmaf(wx, rt.y - rt.x, rt.x);
        float bot = fmaf(wx, rb.y - rb.x, rb.x);
        acc = fmaf(wy, bot - top, acc + top);
#endif
    }
    if (myLo <= myHi) atomicAdd(&out[ray], acc * dt);
}

extern "C" void kernel_launch(void* const* d_in, const int* in_sizes, int n_in,
                              void* d_out, int out_size, void* d_ws, size_t ws_size,
                              hipStream_t stream) {
    const float* x = (const float*)d_in[0];
    float* out     = (float*)d_out;
    uint* hpad     = (uint*)d_ws;                      // NBATCH*2*PHD*4 = 272 KB

    hipMemsetAsync(out, 0, (size_t)out_size * sizeof(float), stream);

    int ndw = NBATCH * 2 * PHD;                        // 68112
    pad_build_kernel<<<(ndw + 255) / 256, 256, 0, stream>>>(x, hpad);

    // 512 blocks = 256 ray-groups x 2 y-halves; 2 blocks/CU co-resident
    fanproj_kernel<<<512, TPB, 0, stream>>>((const uint4*)hpad, out);
}